// Round 2
// baseline (403.312 us; speedup 1.0000x reference)
//
#include <hip/hip_runtime.h>
#include <stdint.h>

// GIN layer, f32 interface (reference is jnp.float32; harness passes f32).
// Internals use bf16 for MFMA GEMMs; BN stats fused into GEMM epilogue.
// h0 = feats + segment_max(feats[src], dst); then Lin->BN->ReLU x2 -> BN.

#define NN 50000
#define NE 800000
#define DD 128
#define BN_EPS 1e-5f
#define NPB 1568   // padded partials stride (>= 1563 gemm blocks)
#define SCAN_B 196 // ceil(50000/256)

typedef short bf16x8 __attribute__((ext_vector_type(8)));
typedef float f32x4 __attribute__((ext_vector_type(4)));

__device__ __forceinline__ float bf2f(unsigned short u) {
    return __uint_as_float(((unsigned int)u) << 16);
}
__device__ __forceinline__ unsigned short f2bf(float f) {
    unsigned int u = __float_as_uint(f);
    u += 0x7fffu + ((u >> 16) & 1u);  // RNE
    return (unsigned short)(u >> 16);
}

// ---------------- CSR build ----------------
__global__ void k_zero(unsigned int* p, int n) {
    int i = blockIdx.x * 256 + threadIdx.x;
    if (i < n) p[i] = 0u;
}

__global__ void k_hist(const int* __restrict__ dst, unsigned int* __restrict__ deg) {
    int e = blockIdx.x * 256 + threadIdx.x;
    if (e < NE) atomicAdd(&deg[dst[e]], 1u);
}

__global__ void k_scan1(const unsigned int* __restrict__ deg,
                        unsigned int* __restrict__ offs,
                        unsigned int* __restrict__ bsum) {
    __shared__ unsigned int lds[256];
    int t = threadIdx.x;
    int idx = blockIdx.x * 256 + t;
    unsigned int v = (idx < NN) ? deg[idx] : 0u;
    lds[t] = v;
    __syncthreads();
    for (int off = 1; off < 256; off <<= 1) {
        unsigned int u = (t >= off) ? lds[t - off] : 0u;
        __syncthreads();
        lds[t] += u;
        __syncthreads();
    }
    unsigned int inc = lds[t];
    if (idx < NN) offs[idx] = inc - v;   // exclusive within block
    if (t == 255) bsum[blockIdx.x] = inc;
}

__global__ void k_scan2(unsigned int* __restrict__ bsum) {
    __shared__ unsigned int lds[256];
    int t = threadIdx.x;
    unsigned int v = (t < SCAN_B) ? bsum[t] : 0u;
    lds[t] = v;
    __syncthreads();
    for (int off = 1; off < 256; off <<= 1) {
        unsigned int u = (t >= off) ? lds[t - off] : 0u;
        __syncthreads();
        lds[t] += u;
        __syncthreads();
    }
    if (t < SCAN_B) bsum[t] = lds[t] - v;  // exclusive block offsets
}

__global__ void k_scan3(unsigned int* __restrict__ offs,
                        const unsigned int* __restrict__ bsum,
                        unsigned int* __restrict__ cursor) {
    int idx = blockIdx.x * 256 + threadIdx.x;
    if (idx < NN) {
        unsigned int o = offs[idx] + bsum[blockIdx.x];
        offs[idx] = o;
        cursor[idx] = o;
    }
}

__global__ void k_scatter(const int* __restrict__ src, const int* __restrict__ dst,
                          unsigned int* __restrict__ cursor, int* __restrict__ csr) {
    int e = blockIdx.x * 256 + threadIdx.x;
    if (e < NE) {
        unsigned int pos = atomicAdd(&cursor[dst[e]], 1u);
        csr[pos] = src[e];
    }
}

// ------------- aggregation: one wave per node, 2 dims/lane (f32 in, bf16 out)
__global__ __launch_bounds__(256) void k_agg(
    const float* __restrict__ feats, const int* __restrict__ csr,
    const unsigned int* __restrict__ offs, const unsigned int* __restrict__ deg,
    unsigned short* __restrict__ h0)
{
    int wave = threadIdx.x >> 6;
    int lane = threadIdx.x & 63;
    int node = blockIdx.x * 4 + wave;
    if (node >= NN) return;
    int d0 = lane * 2;
    unsigned int start = offs[node];
    unsigned int cnt = deg[node];
    float m0 = -3.0e38f, m1 = -3.0e38f;
    for (unsigned int i = 0; i < cnt; ++i) {
        int s = csr[start + i];
        float2 pk = *reinterpret_cast<const float2*>(feats + s * DD + d0);
        m0 = fmaxf(m0, pk.x);
        m1 = fmaxf(m1, pk.y);
    }
    if (cnt == 0u) { m0 = 0.f; m1 = 0.f; }  // no in-edges -> agg = 0
    float2 pf = *reinterpret_cast<const float2*>(feats + node * DD + d0);
    float o0 = pf.x + m0;
    float o1 = pf.y + m1;
    unsigned int o = (unsigned int)f2bf(o0) | ((unsigned int)f2bf(o1) << 16);
    *reinterpret_cast<unsigned int*>(h0 + node * DD + d0) = o;
}

// ------------- W (f32) transpose -> bf16 Wt (stays L1/L2 hot) -------------
__global__ void k_wt(const float* __restrict__ W, unsigned short* __restrict__ Wt) {
    int g = blockIdx.x * 256 + threadIdx.x;  // 0..16383
    int row = g >> 7, col = g & 127;
    Wt[col * DD + row] = f2bf(W[g]);
}

// ------------- GEMM: Y = X @ W + b (bf16 MFMA), + per-column sum/sumsq -------
// block = 256 thr = 4 waves; block covers 32 rows; wave = 16 rows x 64 cols.
// mfma_f32_16x16x32_bf16: A[m=lane&15][k=quad*8+j], B[n=lane&15][k=quad*8+j]
// (B read from Wt = W^T), C/D: col=lane&15, row=quad*4+reg (m89-verified).
__global__ __launch_bounds__(256) void k_gemm(
    const unsigned short* __restrict__ X, const unsigned short* __restrict__ Wt,
    const float* __restrict__ bias, unsigned short* __restrict__ Y,
    float* __restrict__ partials)
{
    __shared__ float lsum[128], lsq[128];
    int tid = threadIdx.x;
    if (tid < 128) { lsum[tid] = 0.f; lsq[tid] = 0.f; }
    __syncthreads();
    int wave = tid >> 6, lane = tid & 63;
    int quad = lane >> 4, l16 = lane & 15;
    int m0 = blockIdx.x * 32 + (wave >> 1) * 16;
    int nh = (wave & 1) * 64;
    int myrow = m0 + l16;
    int kq = quad * 8;

    f32x4 acc[4];
#pragma unroll
    for (int j = 0; j < 4; ++j)
#pragma unroll
        for (int r = 0; r < 4; ++r) acc[j][r] = 0.f;

#pragma unroll
    for (int k0 = 0; k0 < 128; k0 += 32) {
        bf16x8 a;
        if (myrow < NN) {
            a = *reinterpret_cast<const bf16x8*>(X + myrow * DD + k0 + kq);
        } else {
#pragma unroll
            for (int i = 0; i < 8; ++i) a[i] = 0;
        }
#pragma unroll
        for (int j = 0; j < 4; ++j) {
            bf16x8 b = *reinterpret_cast<const bf16x8*>(Wt + (nh + j * 16 + l16) * DD + k0 + kq);
            acc[j] = __builtin_amdgcn_mfma_f32_16x16x32_bf16(a, b, acc[j], 0, 0, 0);
        }
    }

    int rbase = m0 + quad * 4;
#pragma unroll
    for (int j = 0; j < 4; ++j) {
        int col = nh + j * 16 + l16;
        float bcol = bias[col];
        float s = 0.f, q = 0.f;
#pragma unroll
        for (int r = 0; r < 4; ++r) {
            int row = rbase + r;
            if (row < NN) {
                float v = acc[j][r] + bcol;
                Y[row * DD + col] = f2bf(v);
                s += v;
                q += v * v;
            }
        }
        s += __shfl_xor(s, 16, 64);
        s += __shfl_xor(s, 32, 64);
        q += __shfl_xor(q, 16, 64);
        q += __shfl_xor(q, 32, 64);
        if (quad == 0) {
            atomicAdd(&lsum[col], s);
            atomicAdd(&lsq[col], q);
        }
    }
    __syncthreads();
    if (tid < 128) {
        partials[tid * NPB + blockIdx.x] = lsum[tid];
        partials[(128 + tid) * NPB + blockIdx.x] = lsq[tid];
    }
}

// ------------- reduce partials rows -> stats[256] -------------
__global__ void k_red(const float* __restrict__ partials, int nblk, float* __restrict__ stats) {
    __shared__ float lds[256];
    int rowid = blockIdx.x;  // 0..255 (128 sums, then 128 sumsqs)
    float s = 0.f;
    for (int i = threadIdx.x; i < nblk; i += 256) s += partials[rowid * NPB + i];
    lds[threadIdx.x] = s;
    __syncthreads();
    for (int off = 128; off > 0; off >>= 1) {
        if (threadIdx.x < off) lds[threadIdx.x] += lds[threadIdx.x + off];
        __syncthreads();
    }
    if (threadIdx.x == 0) stats[rowid] = lds[0];
}

// ------------- stats -> per-column affine (a, c): bn(x) = a*x + c -------------
__global__ void k_bnparams(const float* __restrict__ stats,
                           const float* __restrict__ g,
                           const float* __restrict__ be,
                           float* __restrict__ a, float* __restrict__ c) {
    int t = threadIdx.x;  // 128
    float mean = stats[t] / (float)NN;
    float var = stats[128 + t] / (float)NN - mean * mean;
    var = fmaxf(var, 0.f);
    float av = g[t] * rsqrtf(var + BN_EPS);
    a[t] = av;
    c[t] = be[t] - mean * av;
}

// ------------- X2 = relu(a*Y + c), bf16 -> bf16 -------------
__global__ __launch_bounds__(256) void k_affine_relu(
    const unsigned short* __restrict__ Yin, const float* __restrict__ aa,
    const float* __restrict__ cc, unsigned short* __restrict__ Xout)
{
    int g = blockIdx.x * 256 + threadIdx.x;
    int base = g * 4;
    int c0 = base & 127;
    uint2 p = *reinterpret_cast<const uint2*>(Yin + base);
    float4 av = *reinterpret_cast<const float4*>(aa + c0);
    float4 cv = *reinterpret_cast<const float4*>(cc + c0);
    float v0 = fmaxf(av.x * bf2f((unsigned short)(p.x & 0xffffu)) + cv.x, 0.f);
    float v1 = fmaxf(av.y * bf2f((unsigned short)(p.x >> 16)) + cv.y, 0.f);
    float v2 = fmaxf(av.z * bf2f((unsigned short)(p.y & 0xffffu)) + cv.z, 0.f);
    float v3 = fmaxf(av.w * bf2f((unsigned short)(p.y >> 16)) + cv.w, 0.f);
    uint2 o;
    o.x = (unsigned int)f2bf(v0) | ((unsigned int)f2bf(v1) << 16);
    o.y = (unsigned int)f2bf(v2) | ((unsigned int)f2bf(v3) << 16);
    *reinterpret_cast<uint2*>(Xout + base) = o;
}

// ------------- stats of z = relu(a2*Y2 + c2) -------------
__global__ __launch_bounds__(256) void k_zstats(
    const unsigned short* __restrict__ Y2, const float* __restrict__ a2,
    const float* __restrict__ c2, float* __restrict__ partials)
{
    __shared__ float ls[256], lq[256];
    int t = threadIdx.x;
    int col = t & 127, half = t >> 7;
    float av = a2[col], cv = c2[col];
    float s = 0.f, q = 0.f;
    for (int row = blockIdx.x * 2 + half; row < NN; row += gridDim.x * 2) {
        float z = fmaxf(av * bf2f(Y2[row * DD + col]) + cv, 0.f);
        s += z;
        q += z * z;
    }
    ls[t] = s;
    lq[t] = q;
    __syncthreads();
    if (t < 128) {
        partials[t * NPB + blockIdx.x] = ls[t] + ls[t + 128];
        partials[(128 + t) * NPB + blockIdx.x] = lq[t] + lq[t + 128];
    }
}

// ------------- out = a3*relu(a2*Y2+c2) + c3, f32 out -------------
__global__ __launch_bounds__(256) void k_out(
    const unsigned short* __restrict__ Y2, const float* __restrict__ a2,
    const float* __restrict__ c2, const float* __restrict__ a3,
    const float* __restrict__ c3, float* __restrict__ out)
{
    int g = blockIdx.x * 256 + threadIdx.x;
    int base = g * 4;
    int c0 = base & 127;
    uint2 p = *reinterpret_cast<const uint2*>(Y2 + base);
    float4 av2 = *reinterpret_cast<const float4*>(a2 + c0);
    float4 cv2 = *reinterpret_cast<const float4*>(c2 + c0);
    float4 av3 = *reinterpret_cast<const float4*>(a3 + c0);
    float4 cv3 = *reinterpret_cast<const float4*>(c3 + c0);
    float z0 = fmaxf(av2.x * bf2f((unsigned short)(p.x & 0xffffu)) + cv2.x, 0.f);
    float z1 = fmaxf(av2.y * bf2f((unsigned short)(p.x >> 16)) + cv2.y, 0.f);
    float z2 = fmaxf(av2.z * bf2f((unsigned short)(p.y & 0xffffu)) + cv2.z, 0.f);
    float z3 = fmaxf(av2.w * bf2f((unsigned short)(p.y >> 16)) + cv2.w, 0.f);
    float4 o;
    o.x = av3.x * z0 + cv3.x;
    o.y = av3.y * z1 + cv3.y;
    o.z = av3.z * z2 + cv3.z;
    o.w = av3.w * z3 + cv3.w;
    *reinterpret_cast<float4*>(out + base) = o;
}

extern "C" void kernel_launch(void* const* d_in, const int* in_sizes, int n_in,
                              void* d_out, int out_size, void* d_ws, size_t ws_size,
                              hipStream_t stream) {
    (void)in_sizes; (void)n_in; (void)out_size; (void)ws_size;
    const float* feats = (const float*)d_in[0];
    const int* src = (const int*)d_in[1];
    const int* dst = (const int*)d_in[2];
    const float* W1 = (const float*)d_in[3];
    const float* b1 = (const float*)d_in[4];
    const float* g1 = (const float*)d_in[5];
    const float* be1 = (const float*)d_in[6];
    const float* W2 = (const float*)d_in[7];
    const float* b2 = (const float*)d_in[8];
    const float* g2 = (const float*)d_in[9];
    const float* be2 = (const float*)d_in[10];
    const float* g3 = (const float*)d_in[11];
    const float* be3 = (const float*)d_in[12];
    float* out = (float*)d_out;

    char* p = (char*)d_ws;
    auto alloc = [&](size_t n) { char* r = p; p += (n + 255) & ~(size_t)255; return r; };
    unsigned int* deg = (unsigned int*)alloc((size_t)NN * 4);
    unsigned int* offs = (unsigned int*)alloc((size_t)NN * 4);
    unsigned int* bsum = (unsigned int*)alloc(256 * 4);
    unsigned int* cursor = (unsigned int*)alloc((size_t)NN * 4);
    int* csr = (int*)alloc((size_t)NE * 4);
    unsigned short* h0 = (unsigned short*)alloc((size_t)NN * DD * 2);
    unsigned short* Y1 = (unsigned short*)alloc((size_t)NN * DD * 2);
    unsigned short* X2 = (unsigned short*)alloc((size_t)NN * DD * 2);
    unsigned short* Y2 = (unsigned short*)alloc((size_t)NN * DD * 2);
    unsigned short* Wt = (unsigned short*)alloc((size_t)DD * DD * 2);
    float* partials = (float*)alloc((size_t)256 * NPB * 4);
    float* stats = (float*)alloc(256 * 4);
    float* a1 = (float*)alloc(DD * 4); float* c1 = (float*)alloc(DD * 4);
    float* a2 = (float*)alloc(DD * 4); float* c2 = (float*)alloc(DD * 4);
    float* a3 = (float*)alloc(DD * 4); float* c3 = (float*)alloc(DD * 4);

    // CSR build
    k_zero<<<SCAN_B, 256, 0, stream>>>(deg, NN);
    k_hist<<<3125, 256, 0, stream>>>(dst, deg);
    k_scan1<<<SCAN_B, 256, 0, stream>>>(deg, offs, bsum);
    k_scan2<<<1, 256, 0, stream>>>(bsum);
    k_scan3<<<SCAN_B, 256, 0, stream>>>(offs, bsum, cursor);
    k_scatter<<<3125, 256, 0, stream>>>(src, dst, cursor, csr);
    // h0 = feats + max-agg (0 for isolated nodes), bf16
    k_agg<<<12500, 256, 0, stream>>>(feats, csr, offs, deg, h0);
    // layer 1
    k_wt<<<64, 256, 0, stream>>>(W1, Wt);
    k_gemm<<<1563, 256, 0, stream>>>(h0, Wt, b1, Y1, partials);
    k_red<<<256, 256, 0, stream>>>(partials, 1563, stats);
    k_bnparams<<<1, 128, 0, stream>>>(stats, g1, be1, a1, c1);
    k_affine_relu<<<6250, 256, 0, stream>>>(Y1, a1, c1, X2);
    // layer 2
    k_wt<<<64, 256, 0, stream>>>(W2, Wt);
    k_gemm<<<1563, 256, 0, stream>>>(X2, Wt, b2, Y2, partials);
    k_red<<<256, 256, 0, stream>>>(partials, 1563, stats);
    k_bnparams<<<1, 128, 0, stream>>>(stats, g2, be2, a2, c2);
    // outer BN over z = relu(a2*Y2+c2)
    k_zstats<<<256, 256, 0, stream>>>(Y2, a2, c2, partials);
    k_red<<<256, 256, 0, stream>>>(partials, 256, stats);
    k_bnparams<<<1, 128, 0, stream>>>(stats, g3, be3, a3, c3);
    k_out<<<6250, 256, 0, stream>>>(Y2, a2, c2, a3, c3, out);
}

// Round 3
// 336.507 us; speedup vs baseline: 1.1985x; 1.1985x over previous
//
#include <hip/hip_runtime.h>
#include <stdint.h>

// GIN layer, f32 interface. Internals bf16 for MFMA GEMMs; BN stats fused
// into GEMM epilogue; layer-1 BN+ReLU fused into gemm2's A-fragment load.
// Aggregation gathers from pre-converted bf16 feats (monotone rounding =>
// max commutes with bf16 conversion), edge loop unrolled x4 for MLP.

#define NN 50000
#define NE 800000
#define DD 128
#define BN_EPS 1e-5f
#define NPB 1568   // padded partials stride (>= 1563 gemm blocks)
#define SCAN_B 196 // ceil(50000/256)

typedef short bf16x8 __attribute__((ext_vector_type(8)));
typedef float f32x4 __attribute__((ext_vector_type(4)));

__device__ __forceinline__ float bf2f(unsigned short u) {
    return __uint_as_float(((unsigned int)u) << 16);
}
__device__ __forceinline__ unsigned short f2bf(float f) {
    unsigned int u = __float_as_uint(f);
    u += 0x7fffu + ((u >> 16) & 1u);  // RNE
    return (unsigned short)(u >> 16);
}
__device__ __forceinline__ float plo(unsigned int p) { return bf2f((unsigned short)(p & 0xffffu)); }
__device__ __forceinline__ float phi(unsigned int p) { return bf2f((unsigned short)(p >> 16)); }

// ---- feats f32 -> bf16 (packed), also zeros deg ----
__global__ __launch_bounds__(256) void k_feat16(const float* __restrict__ feats,
                                                unsigned short* __restrict__ fb,
                                                unsigned int* __restrict__ deg) {
    int g = blockIdx.x * 256 + threadIdx.x;   // 1.6M threads, 4 floats each
    int base = g * 4;
    float4 v = *reinterpret_cast<const float4*>(feats + base);
    uint2 o;
    o.x = (unsigned int)f2bf(v.x) | ((unsigned int)f2bf(v.y) << 16);
    o.y = (unsigned int)f2bf(v.z) | ((unsigned int)f2bf(v.w) << 16);
    *reinterpret_cast<uint2*>(fb + base) = o;
    if (g < NN) deg[g] = 0u;
}

__global__ void k_hist(const int* __restrict__ dst, unsigned int* __restrict__ deg) {
    int e = blockIdx.x * 256 + threadIdx.x;
    if (e < NE) atomicAdd(&deg[dst[e]], 1u);
}

__global__ void k_scan1(const unsigned int* __restrict__ deg,
                        unsigned int* __restrict__ offs,
                        unsigned int* __restrict__ bsum) {
    __shared__ unsigned int lds[256];
    int t = threadIdx.x;
    int idx = blockIdx.x * 256 + t;
    unsigned int v = (idx < NN) ? deg[idx] : 0u;
    lds[t] = v;
    __syncthreads();
    for (int off = 1; off < 256; off <<= 1) {
        unsigned int u = (t >= off) ? lds[t - off] : 0u;
        __syncthreads();
        lds[t] += u;
        __syncthreads();
    }
    unsigned int inc = lds[t];
    if (idx < NN) offs[idx] = inc - v;   // exclusive within block
    if (t == 255) bsum[blockIdx.x] = inc;
}

// scan of block sums done redundantly per block (196 elems, trivial)
__global__ void k_scan3(unsigned int* __restrict__ offs,
                        const unsigned int* __restrict__ bsum,
                        unsigned int* __restrict__ cursor) {
    __shared__ unsigned int lds[256];
    int t = threadIdx.x;
    unsigned int v = (t < SCAN_B) ? bsum[t] : 0u;
    lds[t] = v;
    __syncthreads();
    for (int off = 1; off < 256; off <<= 1) {
        unsigned int u = (t >= off) ? lds[t - off] : 0u;
        __syncthreads();
        lds[t] += u;
        __syncthreads();
    }
    unsigned int blockoff = (blockIdx.x == 0) ? 0u : lds[blockIdx.x - 1];
    int idx = blockIdx.x * 256 + t;
    if (idx < NN) {
        unsigned int o = offs[idx] + blockoff;
        offs[idx] = o;
        cursor[idx] = o;
    }
}

__global__ void k_scatter(const int* __restrict__ src, const int* __restrict__ dst,
                          unsigned int* __restrict__ cursor, int* __restrict__ csr) {
    int e = blockIdx.x * 256 + threadIdx.x;
    if (e < NE) {
        unsigned int pos = atomicAdd(&cursor[dst[e]], 1u);
        csr[pos] = src[e];
    }
}

// ---- aggregation: one wave/node, 2 dims/lane, bf16 gather, unroll x4 ----
__global__ __launch_bounds__(256) void k_agg(
    const unsigned short* __restrict__ fb, const int* __restrict__ csr,
    const unsigned int* __restrict__ offs, const unsigned int* __restrict__ deg,
    unsigned short* __restrict__ h0)
{
    int wave = threadIdx.x >> 6;
    int lane = threadIdx.x & 63;
    int node = blockIdx.x * 4 + wave;
    if (node >= NN) return;
    const unsigned int* F = reinterpret_cast<const unsigned int*>(fb);  // 64 uints/row
    unsigned int start = offs[node];
    unsigned int cnt = deg[node];
    float m0 = -3.0e38f, m1 = -3.0e38f;
    unsigned int i = 0;
    for (; i + 4 <= cnt; i += 4) {
        int s0 = csr[start + i];
        int s1 = csr[start + i + 1];
        int s2 = csr[start + i + 2];
        int s3 = csr[start + i + 3];
        unsigned int p0 = F[s0 * 64 + lane];
        unsigned int p1 = F[s1 * 64 + lane];
        unsigned int p2 = F[s2 * 64 + lane];
        unsigned int p3 = F[s3 * 64 + lane];
        float a0 = fmaxf(plo(p0), plo(p1)), a1 = fmaxf(plo(p2), plo(p3));
        float b0 = fmaxf(phi(p0), phi(p1)), b1 = fmaxf(phi(p2), phi(p3));
        m0 = fmaxf(m0, fmaxf(a0, a1));
        m1 = fmaxf(m1, fmaxf(b0, b1));
    }
    for (; i < cnt; ++i) {
        int s = csr[start + i];
        unsigned int p = F[s * 64 + lane];
        m0 = fmaxf(m0, plo(p));
        m1 = fmaxf(m1, phi(p));
    }
    if (cnt == 0u) { m0 = 0.f; m1 = 0.f; }
    unsigned int pf = F[node * 64 + lane];
    unsigned int o = (unsigned int)f2bf(plo(pf) + m0) | ((unsigned int)f2bf(phi(pf) + m1) << 16);
    reinterpret_cast<unsigned int*>(h0)[node * 64 + lane] = o;
}

// ---- W (f32) transpose -> bf16 Wt ----
__global__ void k_wt(const float* __restrict__ W, unsigned short* __restrict__ Wt) {
    int g = blockIdx.x * 256 + threadIdx.x;  // 0..16383
    int row = g >> 7, col = g & 127;
    Wt[col * DD + row] = f2bf(W[g]);
}

// ---- GEMM: Y = act(X) @ W + b (bf16 MFMA) + per-column sum/sumsq ----
// FUSE=1: A element = relu(pa[k]*x + pc[k])  (layer-1 BN+ReLU applied on load)
// block = 256 thr; 32 rows; wave = 16 rows x 64 cols.
// mfma_f32_16x16x32_bf16: A[m=lane&15][k=quad*8+j], B[n=lane&15][k=quad*8+j],
// C/D: col=lane&15, row=quad*4+reg (m89-verified).
template <int FUSE>
__global__ __launch_bounds__(256) void k_gemm(
    const unsigned short* __restrict__ X, const unsigned short* __restrict__ Wt,
    const float* __restrict__ bias, const float* __restrict__ pa,
    const float* __restrict__ pc, unsigned short* __restrict__ Y,
    float* __restrict__ partials)
{
    __shared__ float lsum[128], lsq[128];
    int tid = threadIdx.x;
    if (tid < 128) { lsum[tid] = 0.f; lsq[tid] = 0.f; }
    __syncthreads();
    int wave = tid >> 6, lane = tid & 63;
    int quad = lane >> 4, l16 = lane & 15;
    int m0 = blockIdx.x * 32 + (wave >> 1) * 16;
    int nh = (wave & 1) * 64;
    int myrow = m0 + l16;
    int kq = quad * 8;

    f32x4 acc[4];
#pragma unroll
    for (int j = 0; j < 4; ++j)
#pragma unroll
        for (int r = 0; r < 4; ++r) acc[j][r] = 0.f;

#pragma unroll
    for (int k0 = 0; k0 < 128; k0 += 32) {
        bf16x8 a;
        if (myrow < NN) {
            a = *reinterpret_cast<const bf16x8*>(X + myrow * DD + k0 + kq);
            if (FUSE) {
                float4 av0 = *reinterpret_cast<const float4*>(pa + k0 + kq);
                float4 av1 = *reinterpret_cast<const float4*>(pa + k0 + kq + 4);
                float4 cv0 = *reinterpret_cast<const float4*>(pc + k0 + kq);
                float4 cv1 = *reinterpret_cast<const float4*>(pc + k0 + kq + 4);
                float fa[8] = {av0.x, av0.y, av0.z, av0.w, av1.x, av1.y, av1.z, av1.w};
                float fc[8] = {cv0.x, cv0.y, cv0.z, cv0.w, cv1.x, cv1.y, cv1.z, cv1.w};
#pragma unroll
                for (int j = 0; j < 8; ++j) {
                    float v = fmaxf(fa[j] * bf2f((unsigned short)a[j]) + fc[j], 0.f);
                    a[j] = (short)f2bf(v);
                }
            }
        } else {
#pragma unroll
            for (int j = 0; j < 8; ++j) a[j] = 0;
        }
#pragma unroll
        for (int j = 0; j < 4; ++j) {
            bf16x8 b = *reinterpret_cast<const bf16x8*>(Wt + (nh + j * 16 + l16) * DD + k0 + kq);
            acc[j] = __builtin_amdgcn_mfma_f32_16x16x32_bf16(a, b, acc[j], 0, 0, 0);
        }
    }

    int rbase = m0 + quad * 4;
#pragma unroll
    for (int j = 0; j < 4; ++j) {
        int col = nh + j * 16 + l16;
        float bcol = bias[col];
        float s = 0.f, q = 0.f;
#pragma unroll
        for (int r = 0; r < 4; ++r) {
            int row = rbase + r;
            if (row < NN) {
                float v = acc[j][r] + bcol;
                Y[row * DD + col] = f2bf(v);
                s += v;
                q += v * v;
            }
        }
        s += __shfl_xor(s, 16, 64);
        s += __shfl_xor(s, 32, 64);
        q += __shfl_xor(q, 16, 64);
        q += __shfl_xor(q, 32, 64);
        if (quad == 0) {
            atomicAdd(&lsum[col], s);
            atomicAdd(&lsq[col], q);
        }
    }
    __syncthreads();
    if (tid < 128) {
        partials[tid * NPB + blockIdx.x] = lsum[tid];
        partials[(128 + tid) * NPB + blockIdx.x] = lsq[tid];
    }
}

// ---- reduce partials + compute BN affine: a = g*rsqrt(var+eps), c = be - mean*a
__global__ void k_redparams(const float* __restrict__ partials, int nblk,
                            const float* __restrict__ g, const float* __restrict__ be,
                            float* __restrict__ a, float* __restrict__ c) {
    __shared__ float ls[256], lq[256];
    int t = threadIdx.x;
    int col = blockIdx.x;  // 0..127
    float s = 0.f, q = 0.f;
    for (int i = t; i < nblk; i += 256) {
        s += partials[col * NPB + i];
        q += partials[(128 + col) * NPB + i];
    }
    ls[t] = s; lq[t] = q;
    __syncthreads();
    for (int off = 128; off > 0; off >>= 1) {
        if (t < off) { ls[t] += ls[t + off]; lq[t] += lq[t + off]; }
        __syncthreads();
    }
    if (t == 0) {
        float mean = ls[0] / (float)NN;
        float var = fmaxf(lq[0] / (float)NN - mean * mean, 0.f);
        float av = g[col] * rsqrtf(var + BN_EPS);
        a[col] = av;
        c[col] = be[col] - mean * av;
    }
}

// ---- stats of z = relu(a2*Y2 + c2) ----
__global__ __launch_bounds__(256) void k_zstats(
    const unsigned short* __restrict__ Y2, const float* __restrict__ a2,
    const float* __restrict__ c2, float* __restrict__ partials)
{
    __shared__ float ls[256], lq[256];
    int t = threadIdx.x;
    int col = t & 127, half = t >> 7;
    float av = a2[col], cv = c2[col];
    float s = 0.f, q = 0.f;
    for (int row = blockIdx.x * 2 + half; row < NN; row += gridDim.x * 2) {
        float z = fmaxf(av * bf2f(Y2[row * DD + col]) + cv, 0.f);
        s += z;
        q += z * z;
    }
    ls[t] = s;
    lq[t] = q;
    __syncthreads();
    if (t < 128) {
        partials[t * NPB + blockIdx.x] = ls[t] + ls[t + 128];
        partials[(128 + t) * NPB + blockIdx.x] = lq[t] + lq[t + 128];
    }
}

// ---- out = a3*relu(a2*Y2+c2) + c3, f32 out ----
__global__ __launch_bounds__(256) void k_out(
    const unsigned short* __restrict__ Y2, const float* __restrict__ a2,
    const float* __restrict__ c2, const float* __restrict__ a3,
    const float* __restrict__ c3, float* __restrict__ out)
{
    int g = blockIdx.x * 256 + threadIdx.x;
    int base = g * 4;
    int c0 = base & 127;
    uint2 p = *reinterpret_cast<const uint2*>(Y2 + base);
    float4 av2 = *reinterpret_cast<const float4*>(a2 + c0);
    float4 cv2 = *reinterpret_cast<const float4*>(c2 + c0);
    float4 av3 = *reinterpret_cast<const float4*>(a3 + c0);
    float4 cv3 = *reinterpret_cast<const float4*>(c3 + c0);
    float z0 = fmaxf(av2.x * plo(p.x) + cv2.x, 0.f);
    float z1 = fmaxf(av2.y * phi(p.x) + cv2.y, 0.f);
    float z2 = fmaxf(av2.z * plo(p.y) + cv2.z, 0.f);
    float z3 = fmaxf(av2.w * phi(p.y) + cv2.w, 0.f);
    float4 o;
    o.x = av3.x * z0 + cv3.x;
    o.y = av3.y * z1 + cv3.y;
    o.z = av3.z * z2 + cv3.z;
    o.w = av3.w * z3 + cv3.w;
    *reinterpret_cast<float4*>(out + base) = o;
}

extern "C" void kernel_launch(void* const* d_in, const int* in_sizes, int n_in,
                              void* d_out, int out_size, void* d_ws, size_t ws_size,
                              hipStream_t stream) {
    (void)in_sizes; (void)n_in; (void)out_size; (void)ws_size;
    const float* feats = (const float*)d_in[0];
    const int* src = (const int*)d_in[1];
    const int* dst = (const int*)d_in[2];
    const float* W1 = (const float*)d_in[3];
    const float* b1 = (const float*)d_in[4];
    const float* g1 = (const float*)d_in[5];
    const float* be1 = (const float*)d_in[6];
    const float* W2 = (const float*)d_in[7];
    const float* b2 = (const float*)d_in[8];
    const float* g2 = (const float*)d_in[9];
    const float* be2 = (const float*)d_in[10];
    const float* g3 = (const float*)d_in[11];
    const float* be3 = (const float*)d_in[12];
    float* out = (float*)d_out;

    char* p = (char*)d_ws;
    auto alloc = [&](size_t n) { char* r = p; p += (n + 255) & ~(size_t)255; return r; };
    unsigned int* deg = (unsigned int*)alloc((size_t)NN * 4);
    unsigned int* offs = (unsigned int*)alloc((size_t)NN * 4);
    unsigned int* bsum = (unsigned int*)alloc(256 * 4);
    unsigned int* cursor = (unsigned int*)alloc((size_t)NN * 4);
    int* csr = (int*)alloc((size_t)NE * 4);
    unsigned short* fb = (unsigned short*)alloc((size_t)NN * DD * 2);
    unsigned short* h0 = (unsigned short*)alloc((size_t)NN * DD * 2);
    unsigned short* Y1 = (unsigned short*)alloc((size_t)NN * DD * 2);
    unsigned short* Y2 = (unsigned short*)alloc((size_t)NN * DD * 2);
    unsigned short* Wt = (unsigned short*)alloc((size_t)DD * DD * 2);
    float* partials = (float*)alloc((size_t)256 * NPB * 4);
    float* a1 = (float*)alloc(DD * 4); float* c1 = (float*)alloc(DD * 4);
    float* a2 = (float*)alloc(DD * 4); float* c2 = (float*)alloc(DD * 4);
    float* a3 = (float*)alloc(DD * 4); float* c3 = (float*)alloc(DD * 4);

    // feats -> bf16 (+ zero deg); CSR build
    k_feat16<<<6250, 256, 0, stream>>>(feats, fb, deg);
    k_hist<<<3125, 256, 0, stream>>>(dst, deg);
    k_scan1<<<SCAN_B, 256, 0, stream>>>(deg, offs, bsum);
    k_scan3<<<SCAN_B, 256, 0, stream>>>(offs, bsum, cursor);
    k_scatter<<<3125, 256, 0, stream>>>(src, dst, cursor, csr);
    // h0 = feats + max-agg (0 for isolated nodes), bf16
    k_agg<<<12500, 256, 0, stream>>>(fb, csr, offs, deg, h0);
    // layer 1
    k_wt<<<64, 256, 0, stream>>>(W1, Wt);
    k_gemm<0><<<1563, 256, 0, stream>>>(h0, Wt, b1, nullptr, nullptr, Y1, partials);
    k_redparams<<<128, 256, 0, stream>>>(partials, 1563, g1, be1, a1, c1);
    // layer 2 (BN1+ReLU fused into A-load)
    k_wt<<<64, 256, 0, stream>>>(W2, Wt);
    k_gemm<1><<<1563, 256, 0, stream>>>(Y1, Wt, b2, a1, c1, Y2, partials);
    k_redparams<<<128, 256, 0, stream>>>(partials, 1563, g2, be2, a2, c2);
    // outer BN over z = relu(a2*Y2+c2)
    k_zstats<<<256, 256, 0, stream>>>(Y2, a2, c2, partials);
    k_redparams<<<128, 256, 0, stream>>>(partials, 256, g3, be3, a3, c3);
    k_out<<<6250, 256, 0, stream>>>(Y2, a2, c2, a3, c3, out);
}